// Round 7
// baseline (2952.588 us; speedup 1.0000x reference)
//
#include <hip/hip_runtime.h>
#include <hip/hip_bf16.h>

#define S 4096
#define E 256
#define HH 256
#define TT 16
#define NEG_ -10000.0f
#define START_ 14
#define STOP_ 15

// ---------- fast math helpers (host-side kernels) ----------
__device__ __forceinline__ float fast_exp(float x) {           // e^x
    return __builtin_amdgcn_exp2f(x * 1.4426950408889634f);
}
__device__ __forceinline__ float fast_log(float x) {           // ln
    return 0.6931471805599453f * __builtin_amdgcn_logf(x);
}

// ---------- K0: quantize W_hh to int4 (per-row scale m/7); h0 FIXED 1/7 ----------
// One wave per row; lanes 0..31 each pack 8 consecutive values into 1 dword.
__global__ __launch_bounds__(64) void quant4_kernel(
    const float* __restrict__ Wf, const float* __restrict__ Wb,
    const float* __restrict__ h0,
    int* __restrict__ wq4, float* __restrict__ wscale,
    int* __restrict__ hq0p, float* __restrict__ sh0)
{
    int blk = blockIdx.x, lane = threadIdx.x;
    const float* src;
    int* dst;
    float* scl;
    bool fixed = false;
    if (blk < 2048) {
        int d = blk >> 10, r = blk & 1023;
        src = (d == 0 ? Wf : Wb) + (size_t)r * 256;
        dst = wq4 + ((size_t)(d * 1024 + r)) * 32;
        scl = wscale + (d * 1024 + r);
    } else {
        int d = blk - 2048;
        src = h0 + (size_t)d * 256;
        dst = hq0p + d * 32;
        scl = sh0 + d;
        fixed = true;   // h0 quantized at steady-state scale 1/7 (clamped)
    }
    float4 a = make_float4(0.f, 0.f, 0.f, 0.f), b = a;
    if (lane < 32) {
        a = ((const float4*)src)[2 * lane];
        b = ((const float4*)src)[2 * lane + 1];
    }
    float f[8] = {a.x, a.y, a.z, a.w, b.x, b.y, b.z, b.w};
    float m = 0.f;
    #pragma unroll
    for (int k = 0; k < 8; ++k) m = fmaxf(m, fabsf(f[k]));
    #pragma unroll
    for (int off = 1; off < 64; off <<= 1) m = fmaxf(m, __shfl_xor(m, off, 64));
    m = fmaxf(m, 1e-20f);
    float inv = fixed ? 7.0f : (7.0f / m);
    if (lane < 32) {
        int dw = 0;
        #pragma unroll
        for (int k = 0; k < 8; ++k) {
            int q = __float2int_rn(f[k] * inv);
            q = max(-8, min(7, q));
            dw |= (q & 0xF) << (4 * k);
        }
        dst[lane] = dw;
    }
    if (lane == 0) *scl = fixed ? (1.0f / 7.0f) : (m / 7.0f);
}

// ---------- K1: xg packed so lstm thread t (= cell*4+gate) reads dword t ----------
__global__ __launch_bounds__(256) void xg_kernel(
    const int* __restrict__ sent, const float* __restrict__ embed,
    const float* __restrict__ Wf, const float* __restrict__ bihf, const float* __restrict__ bhhf,
    const float* __restrict__ Wb, const float* __restrict__ bihb, const float* __restrict__ bhhb,
    float* __restrict__ xg)
{
    const int dir = blockIdx.y;
    const int t0 = blockIdx.x * 16;
    const int tid = threadIdx.x;
    const float* W = dir ? Wb : Wf;
    __shared__ float xt[16][256];
    for (int tt = 0; tt < 16; ++tt) {
        int t = t0 + tt;
        int pos = dir ? (S - 1 - t) : t;
        int w = sent[pos];
        xt[tt][tid] = embed[(size_t)w * 256 + tid];
    }
    __syncthreads();
    float acc[4][16];
    #pragma unroll
    for (int rc = 0; rc < 4; ++rc)
        #pragma unroll
        for (int tt = 0; tt < 16; ++tt) acc[rc][tt] = 0.f;
    for (int e = 0; e < 256; ++e) {
        float xv[16];
        #pragma unroll
        for (int tt = 0; tt < 16; ++tt) xv[tt] = xt[tt][e];
        #pragma unroll
        for (int rc = 0; rc < 4; ++rc) {
            float w = W[(size_t)(rc * 256 + tid) * 256 + e];
            #pragma unroll
            for (int tt = 0; tt < 16; ++tt) acc[rc][tt] += w * xv[tt];
        }
    }
    const float* bih = dir ? bihb : bihf;
    const float* bhh = dir ? bhhb : bhhf;
    float b0 = bih[0 * 256 + tid] + bhh[0 * 256 + tid];
    float b1 = bih[1 * 256 + tid] + bhh[1 * 256 + tid];
    float b2 = bih[2 * 256 + tid] + bhh[2 * 256 + tid];
    float b3 = bih[3 * 256 + tid] + bhh[3 * 256 + tid];
    #pragma unroll
    for (int tt = 0; tt < 16; ++tt) {
        float4 v;
        v.x = acc[0][tt] + b0;
        v.y = acc[1][tt] + b1;
        v.z = acc[2][tt] + b2;
        v.w = acc[3][tt] + b3;
        ((float4*)(xg + ((size_t)dir * S + (t0 + tt)) * 1024))[tid] = v;
    }
}

// ---------- K2: sequential LSTM, 1024 threads, 1 gate-row/thread, int4 dot8 ----------
// tid t: cell m=t>>2, gate g=t&3 (0=i,1=f,2=g,3=o), row r=g*256+m.
// Weights v32-63 (32 dwords int4). h v64-95 (uniform LDS b128 reads).
// accs v96-97; xA v98, xN v99; addrs v100-103; temps v104-112; delta v113; c v114.
// Gate combine: 3 DPP quad-perms (valid on quad-leader g==0 only); non-leaders
// store to dump regions (branchless). h-pack: 2 cells/byte via ds_swizzle xor-4.
#define D8(a,w,h) "v_dot8_i32_i4 " a ", " w ", " h ", " a "\n\t"

#define LSTM_BODY(XA, XN) \
  "global_load_dword " XN ", v100, %[sxg]\n\t" \
  "ds_read_b128 v[64:67], v102\n\t" \
  "ds_read_b128 v[68:71], v102 offset:16\n\t" \
  "ds_read_b128 v[72:75], v102 offset:32\n\t" \
  "ds_read_b128 v[76:79], v102 offset:48\n\t" \
  "ds_read_b128 v[80:83], v102 offset:64\n\t" \
  "ds_read_b128 v[84:87], v102 offset:80\n\t" \
  "ds_read_b128 v[88:91], v102 offset:96\n\t" \
  "ds_read_b128 v[92:95], v102 offset:112\n\t" \
  "v_mov_b32 v96, 0\n\t" \
  "v_mov_b32 v97, 0\n\t" \
  "s_waitcnt lgkmcnt(6)\n\t" \
  D8("v96","v32","v64") D8("v97","v33","v65") D8("v96","v34","v66") D8("v97","v35","v67") \
  D8("v96","v36","v68") D8("v97","v37","v69") D8("v96","v38","v70") D8("v97","v39","v71") \
  "s_waitcnt lgkmcnt(4)\n\t" \
  D8("v96","v40","v72") D8("v97","v41","v73") D8("v96","v42","v74") D8("v97","v43","v75") \
  D8("v96","v44","v76") D8("v97","v45","v77") D8("v96","v46","v78") D8("v97","v47","v79") \
  "s_waitcnt lgkmcnt(2)\n\t" \
  D8("v96","v48","v80") D8("v97","v49","v81") D8("v96","v50","v82") D8("v97","v51","v83") \
  D8("v96","v52","v84") D8("v97","v53","v85") D8("v96","v54","v86") D8("v97","v55","v87") \
  "s_waitcnt lgkmcnt(0)\n\t" \
  D8("v96","v56","v88") D8("v97","v57","v89") D8("v96","v58","v90") D8("v97","v59","v91") \
  D8("v96","v60","v92") D8("v97","v61","v93") D8("v96","v62","v94") D8("v97","v63","v95") \
  "v_add_u32 v96, v96, v97\n\t" \
  "v_cvt_f32_i32 v104, v96\n\t" \
  "s_waitcnt vmcnt(2)\n\t" \
  "v_fma_f32 v105, %[sc], v104, " XA "\n\t" \
  "v_med3_f32 v105, v105, %[ncl], %[pcl]\n\t" \
  "v_mul_f32 v104, %[kk], v105\n\t" \
  "v_exp_f32 v104, v104\n\t" \
  "s_nop 1\n\t" \
  "v_fma_f32 v106, v104, %[mk], %[bk]\n\t" \
  "v_add_f32 v107, 1.0, v104\n\t" \
  "v_rcp_f32 v107, v107\n\t" \
  "s_nop 1\n\t" \
  "v_mul_f32 v108, v106, v107\n\t" \
  "s_nop 1\n\t" \
  "v_mov_b32_dpp v109, v108 quad_perm:[1,0,3,2] row_mask:0xf bank_mask:0xf\n\t" \
  "v_mov_b32_dpp v110, v108 quad_perm:[2,3,0,1] row_mask:0xf bank_mask:0xf\n\t" \
  "v_mov_b32_dpp v111, v108 quad_perm:[3,2,1,0] row_mask:0xf bank_mask:0xf\n\t" \
  "v_mul_f32 v114, v109, v114\n\t" \
  "v_fmac_f32 v114, v108, v110\n\t" \
  "v_med3_f32 v104, v114, %[ncl], %[pcl]\n\t" \
  "v_mul_f32 v104, %[k2], v104\n\t" \
  "v_exp_f32 v104, v104\n\t" \
  "s_nop 1\n\t" \
  "v_add_f32 v106, -1.0, v104\n\t" \
  "v_add_f32 v107, 1.0, v104\n\t" \
  "v_rcp_f32 v107, v107\n\t" \
  "s_nop 1\n\t" \
  "v_mul_f32 v106, v106, v107\n\t" \
  "v_mul_f32 v112, v111, v106\n\t" \
  "global_store_dword v101, v112, %[shs]\n\t" \
  "v_mul_f32 v104, %[c7], v112\n\t" \
  "v_rndne_f32 v104, v104\n\t" \
  "v_cvt_i32_f32 v104, v104\n\t" \
  "v_and_b32 v104, 15, v104\n\t" \
  "ds_swizzle_b32 v105, v104 offset:0x101F\n\t" \
  "s_waitcnt lgkmcnt(0)\n\t" \
  "v_lshlrev_b32 v105, 4, v105\n\t" \
  "v_or_b32 v104, v104, v105\n\t" \
  "ds_write_b8 v103, v104\n\t" \
  "v_add_u32 v100, 0x1000, v100\n\t" \
  "v_add_u32 v101, v113, v101\n\t" \
  "v_xor_b32 v102, 0x80, v102\n\t" \
  "v_xor_b32 v103, 0x80, v103\n\t" \
  "s_waitcnt lgkmcnt(0)\n\t" \
  "s_barrier\n\t"

__global__ __launch_bounds__(1024, 4) void lstm_kernel(
    const float* __restrict__ xg, const int* __restrict__ wq4,
    const float* __restrict__ wscale, const int* __restrict__ hq0p,
    const float* __restrict__ c0, float* __restrict__ hs,
    unsigned dump_off_bytes)
{
    const int d = blockIdx.x;
    const int t = threadIdx.x;
    const int m = t >> 2;          // cell 0..255
    const int g = t & 3;           // gate 0=i,1=f,2=g,3=o
    const int r = g * 256 + m;     // gate-row

    __shared__ alignas(16) int hq4buf[128];   // 512B: buf0 @0, buf1 @128, dump @256

    const int*   wq_d = wq4 + (size_t)d * 32768;
    const float* xg_d = xg + (size_t)d * S * 1024;
    float*       hs_d = hs + (size_t)d * S * 256;
    const float sc  = wscale[d * 1024 + r] * (1.0f / 7.0f);
    const float c0v = c0[d * 256 + m];
    const int h0v = hq0p[d * 32 + (t & 31)];
    const unsigned h0a = (t < 32) ? (unsigned)t * 4u : (256u + (unsigned)(t & 63) * 4u);
    const unsigned xai = (unsigned)t * 4u;
    const bool leader = (g == 0);
    // non-leaders dump into a scratch region of ws (offset relative to hs_d)
    const unsigned dump_rel = dump_off_bytes - (unsigned)((size_t)d * S * 256 * 4);
    const unsigned hsi = leader ? (unsigned)m * 4u : (dump_rel + (unsigned)(t & 255) * 4u);
    const unsigned dlt = leader ? 1024u : 0u;
    const unsigned hwi = ((t & 7) == 0) ? (128u + (unsigned)(t >> 3))
                                        : (256u + (unsigned)(t & 63) * 4u);
    const unsigned voW = (unsigned)r * 128u;
    const float kk = (g == 2) ? 2.8853900817779268f : -1.4426950408889634f;
    const float mk = (g == 2) ? 1.0f : 0.0f;
    const float bk = (g == 2) ? -1.0f : 1.0f;
    const float k2 = 2.8853900817779268f;
    const float c7 = 7.0f;
    const float ncl = -30.0f, pcl = 30.0f;
    const unsigned lds_keep = (unsigned)(size_t)&hq4buf[0];
    int cnt = S / 2;   // body unrolled x2

    asm volatile(
        // ---- prologue ----
        "v_mov_b32 v100, %[xai]\n\t"
        "v_mov_b32 v101, %[hsi]\n\t"
        "v_mov_b32 v102, 0\n\t"
        "v_mov_b32 v103, %[hwi]\n\t"
        "v_mov_b32 v113, %[dlt]\n\t"
        "v_mov_b32 v114, %[c0v]\n\t"
        "ds_write_b32 %[h0a], %[h0v]\n\t"
        "global_load_dwordx4 v[32:35], %[voW], %[swq]\n\t"
        "global_load_dwordx4 v[36:39], %[voW], %[swq] offset:16\n\t"
        "global_load_dwordx4 v[40:43], %[voW], %[swq] offset:32\n\t"
        "global_load_dwordx4 v[44:47], %[voW], %[swq] offset:48\n\t"
        "global_load_dwordx4 v[48:51], %[voW], %[swq] offset:64\n\t"
        "global_load_dwordx4 v[52:55], %[voW], %[swq] offset:80\n\t"
        "global_load_dwordx4 v[56:59], %[voW], %[swq] offset:96\n\t"
        "global_load_dwordx4 v[60:63], %[voW], %[swq] offset:112\n\t"
        "global_load_dword v98, v100, %[sxg]\n\t"
        "v_add_u32 v100, 0x1000, v100\n\t"
        "s_waitcnt vmcnt(0) lgkmcnt(0)\n\t"
        "s_barrier\n\t"
        // ---- main loop: 2 steps per iteration ----
        "Llstm%=:\n\t"
        LSTM_BODY("v98", "v99")
        LSTM_BODY("v99", "v98")
        "s_add_i32 %[cnt], %[cnt], -1\n\t"
        "s_cmp_lg_u32 %[cnt], 0\n\t"
        "s_cbranch_scc1 Llstm%=\n\t"
        : [cnt] "+s"(cnt)
        : [sxg] "s"(xg_d), [shs] "s"(hs_d), [swq] "s"(wq_d),
          [xai] "v"(xai), [hsi] "v"(hsi), [hwi] "v"(hwi), [dlt] "v"(dlt),
          [c0v] "v"(c0v), [h0a] "v"(h0a), [h0v] "v"(h0v),
          [sc] "v"(sc), [kk] "v"(kk), [mk] "v"(mk), [bk] "v"(bk),
          [k2] "v"(k2), [c7] "v"(c7), [ncl] "v"(ncl), [pcl] "v"(pcl),
          [voW] "v"(voW), [keep] "v"(lds_keep)
        : "memory", "scc",
          "v32","v33","v34","v35","v36","v37","v38","v39",
          "v40","v41","v42","v43","v44","v45","v46","v47",
          "v48","v49","v50","v51","v52","v53","v54","v55",
          "v56","v57","v58","v59","v60","v61","v62","v63",
          "v64","v65","v66","v67","v68","v69","v70","v71",
          "v72","v73","v74","v75","v76","v77","v78","v79",
          "v80","v81","v82","v83","v84","v85","v86","v87",
          "v88","v89","v90","v91","v92","v93","v94","v95",
          "v96","v97","v98","v99","v100","v101","v102","v103",
          "v104","v105","v106","v107","v108","v109","v110","v111",
          "v112","v113","v114");
}

// ---------- K3: feats[t][tag] = b_out[tag] + W_out[tag] . [hf[t], hb[t]] ----------
__global__ __launch_bounds__(256) void feats_kernel(
    const float* __restrict__ hs, const float* __restrict__ Wout,
    const float* __restrict__ bout, float* __restrict__ feats)
{
    __shared__ float Wl[16][513];
    int tid = threadIdx.x;
    for (int i = tid; i < 16 * 512; i += 256) Wl[i >> 9][i & 511] = Wout[i];
    __syncthreads();
    int tt = tid >> 4, tag = tid & 15;
    int tcur = blockIdx.x * 16 + tt;
    const float* hf = hs + (size_t)tcur * 256;
    const float* hb = hs + (size_t)S * 256 + (size_t)(S - 1 - tcur) * 256;
    float acc = bout[tag];
    for (int k = 0; k < 256; ++k) acc += Wl[tag][k] * hf[k];
    for (int k = 0; k < 256; ++k) acc += Wl[tag][256 + k] * hb[k];
    feats[(size_t)tcur * 16 + tag] = acc;
}

// ---------- K4a: CRF chunk products in log semiring ----------
__global__ __launch_bounds__(256) void crf_chunk_kernel(
    const float* __restrict__ feats, const float* __restrict__ trans,
    float* __restrict__ P)
{
    int chunk = blockIdx.x;
    int tid = threadIdx.x;
    int i = tid >> 4, jj = tid & 15;
    __shared__ float Mt[2][16][17];   // Mt[buf][j][k] = M[k][j]
    float tr[16];
    #pragma unroll
    for (int k = 0; k < 16; ++k) tr[k] = trans[i * 16 + k];
    int t0 = chunk * 64;
    float emit = feats[(size_t)t0 * 16 + i];
    Mt[0][jj][i] = tr[jj] + emit;     // init M = A_{t0}
    __syncthreads();
    int cur = 0;
    float em_next = feats[(size_t)(t0 + 1) * 16 + i];
    for (int s = 1; s < 64; ++s) {
        float em = em_next;
        if (s + 1 < 64) em_next = feats[(size_t)(t0 + s + 1) * 16 + i];
        float v[16];
        #pragma unroll
        for (int k = 0; k < 16; ++k) v[k] = tr[k] + Mt[cur][jj][k];
        float m = v[0];
        #pragma unroll
        for (int k = 1; k < 16; ++k) m = fmaxf(m, v[k]);
        float ssum = 0.f;
        #pragma unroll
        for (int k = 0; k < 16; ++k) ssum += fast_exp(v[k] - m);
        float nv = em + m + fast_log(ssum);
        Mt[cur ^ 1][jj][i] = nv;
        cur ^= 1;
        __syncthreads();
    }
    P[((size_t)chunk * 16 + i) * 16 + jj] = Mt[cur][jj][i];
}

// ---------- K4b: fold 64 chunk matrices through alpha ----------
__global__ __launch_bounds__(256) void crf_fold_kernel(
    const float* __restrict__ P, const float* __restrict__ trans,
    float* __restrict__ out)
{
    int tid = threadIdx.x;
    int i = tid >> 4, jj = tid & 15;
    __shared__ float alpha[16];
    if (tid < 16) alpha[tid] = (tid == START_) ? 0.0f : NEG_;
    __syncthreads();
    for (int cc = 0; cc < 64; ++cc) {
        float pv = P[((size_t)cc * 16 + i) * 16 + jj];
        float v = pv + alpha[jj];
        float m = v;
        #pragma unroll
        for (int off = 1; off < 16; off <<= 1) m = fmaxf(m, __shfl_xor(m, off, 64));
        float e = fast_exp(v - m);
        #pragma unroll
        for (int off = 1; off < 16; off <<= 1) e += __shfl_xor(e, off, 64);
        float nv = m + fast_log(e);
        __syncthreads();
        if (jj == 0) alpha[i] = nv;
        __syncthreads();
    }
    if (tid < 16) {
        float v = alpha[tid] + trans[STOP_ * 16 + tid];
        float m = v;
        #pragma unroll
        for (int off = 1; off < 16; off <<= 1) m = fmaxf(m, __shfl_xor(m, off, 64));
        float e = fast_exp(v - m);
        #pragma unroll
        for (int off = 1; off < 16; off <<= 1) e += __shfl_xor(e, off, 64);
        if (tid == 0) out[0] = m + fast_log(e);
    }
}

extern "C" void kernel_launch(void* const* d_in, const int* in_sizes, int n_in,
                              void* d_out, int out_size, void* d_ws, size_t ws_size,
                              hipStream_t stream) {
    const int*   sent  = (const int*)d_in[0];
    const float* embed = (const float*)d_in[1];
    const float* Wihf  = (const float*)d_in[2];
    const float* Whhf  = (const float*)d_in[3];
    const float* bihf  = (const float*)d_in[4];
    const float* bhhf  = (const float*)d_in[5];
    const float* Wihb  = (const float*)d_in[6];
    const float* Whhb  = (const float*)d_in[7];
    const float* bihb  = (const float*)d_in[8];
    const float* bhhb  = (const float*)d_in[9];
    const float* Wout  = (const float*)d_in[10];
    const float* bout  = (const float*)d_in[11];
    const float* trans = (const float*)d_in[12];
    const float* h0    = (const float*)d_in[13];
    const float* c0    = (const float*)d_in[14];
    float* out = (float*)d_out;

    char* ws = (char*)d_ws;
    constexpr size_t OFF_XG     = 0;                                      // 32MB
    constexpr size_t OFF_WQ     = OFF_XG + (size_t)2 * S * 1024 * 4;      // 256KB (int4)
    constexpr size_t OFF_WSCALE = OFF_WQ + (size_t)2 * 1024 * 32 * 4;     // 8KB
    constexpr size_t OFF_HQ0    = OFF_WSCALE + 2 * 1024 * 4;              // 256B
    constexpr size_t OFF_SH0    = OFF_HQ0 + 2 * 32 * 4;                   // pad 256B
    constexpr size_t OFF_HS     = OFF_SH0 + 256;                          // 8MB
    constexpr size_t OFF_DUMP   = OFF_HS + (size_t)2 * S * 256 * 4;       // 4KB dump
    constexpr size_t OFF_FEATS  = OFF_DUMP + 4096;                        // 256KB
    constexpr size_t OFF_P      = OFF_FEATS + (size_t)S * 16 * 4;         // 64KB

    float* xg     = (float*)(ws + OFF_XG);
    int*   wq4    = (int*)(ws + OFF_WQ);
    float* wscale = (float*)(ws + OFF_WSCALE);
    int*   hq0p   = (int*)(ws + OFF_HQ0);
    float* sh0    = (float*)(ws + OFF_SH0);
    float* hs     = (float*)(ws + OFF_HS);
    float* feats  = (float*)(ws + OFF_FEATS);
    float* P      = (float*)(ws + OFF_P);
    const unsigned dump_off = (unsigned)(OFF_DUMP - OFF_HS);  // relative to hs base

    quant4_kernel<<<dim3(2050), dim3(64), 0, stream>>>(Whhf, Whhb, h0, wq4, wscale, hq0p, sh0);
    xg_kernel<<<dim3(256, 2), dim3(256), 0, stream>>>(sent, embed, Wihf, bihf, bhhf,
                                                      Wihb, bihb, bhhb, xg);
    lstm_kernel<<<dim3(2), dim3(1024), 0, stream>>>(xg, wq4, wscale, hq0p, c0, hs, dump_off);
    feats_kernel<<<dim3(256), dim3(256), 0, stream>>>(hs, Wout, bout, feats);
    crf_chunk_kernel<<<dim3(64), dim3(256), 0, stream>>>(feats, trans, P);
    crf_fold_kernel<<<dim3(1), dim3(256), 0, stream>>>(P, trans, out);
}

// Round 8
// 2361.843 us; speedup vs baseline: 1.2501x; 1.2501x over previous
//
#include <hip/hip_runtime.h>
#include <hip/hip_bf16.h>

#define S 4096
#define E 256
#define HH 256
#define TT 16
#define NEG_ -10000.0f
#define START_ 14
#define STOP_ 15

// ---------- fast math helpers (host-side kernels) ----------
__device__ __forceinline__ float fast_exp(float x) {           // e^x
    return __builtin_amdgcn_exp2f(x * 1.4426950408889634f);
}
__device__ __forceinline__ float fast_log(float x) {           // ln
    return 0.6931471805599453f * __builtin_amdgcn_logf(x);
}

// ---------- K0: quantize W_hh to int4 (per-row scale m/7); h0 FIXED 1/7 ----------
__global__ __launch_bounds__(64) void quant4_kernel(
    const float* __restrict__ Wf, const float* __restrict__ Wb,
    const float* __restrict__ h0,
    int* __restrict__ wq4, float* __restrict__ wscale,
    int* __restrict__ hq0p, float* __restrict__ sh0)
{
    int blk = blockIdx.x, lane = threadIdx.x;
    const float* src;
    int* dst;
    float* scl;
    bool fixed = false;
    if (blk < 2048) {
        int d = blk >> 10, r = blk & 1023;
        src = (d == 0 ? Wf : Wb) + (size_t)r * 256;
        dst = wq4 + ((size_t)(d * 1024 + r)) * 32;
        scl = wscale + (d * 1024 + r);
    } else {
        int d = blk - 2048;
        src = h0 + (size_t)d * 256;
        dst = hq0p + d * 32;
        scl = sh0 + d;
        fixed = true;   // h0 quantized at steady-state scale 1/7 (clamped)
    }
    float4 a = make_float4(0.f, 0.f, 0.f, 0.f), b = a;
    if (lane < 32) {
        a = ((const float4*)src)[2 * lane];
        b = ((const float4*)src)[2 * lane + 1];
    }
    float f[8] = {a.x, a.y, a.z, a.w, b.x, b.y, b.z, b.w};
    float m = 0.f;
    #pragma unroll
    for (int k = 0; k < 8; ++k) m = fmaxf(m, fabsf(f[k]));
    #pragma unroll
    for (int off = 1; off < 64; off <<= 1) m = fmaxf(m, __shfl_xor(m, off, 64));
    m = fmaxf(m, 1e-20f);
    float inv = fixed ? 7.0f : (7.0f / m);
    if (lane < 32) {
        int dw = 0;
        #pragma unroll
        for (int k = 0; k < 8; ++k) {
            int q = __float2int_rn(f[k] * inv);
            q = max(-8, min(7, q));
            dw |= (q & 0xF) << (4 * k);
        }
        dst[lane] = dw;
    }
    if (lane == 0) *scl = fixed ? (1.0f / 7.0f) : (m / 7.0f);
}

// ---------- K1: xg stored float4 {i,f,g,o} per cell; lstm thread m reads 16B ----------
__global__ __launch_bounds__(256) void xg_kernel(
    const int* __restrict__ sent, const float* __restrict__ embed,
    const float* __restrict__ Wf, const float* __restrict__ bihf, const float* __restrict__ bhhf,
    const float* __restrict__ Wb, const float* __restrict__ bihb, const float* __restrict__ bhhb,
    float* __restrict__ xg)
{
    const int dir = blockIdx.y;
    const int t0 = blockIdx.x * 16;
    const int tid = threadIdx.x;
    const float* W = dir ? Wb : Wf;
    __shared__ float xt[16][256];
    for (int tt = 0; tt < 16; ++tt) {
        int t = t0 + tt;
        int pos = dir ? (S - 1 - t) : t;
        int w = sent[pos];
        xt[tt][tid] = embed[(size_t)w * 256 + tid];
    }
    __syncthreads();
    float acc[4][16];
    #pragma unroll
    for (int rc = 0; rc < 4; ++rc)
        #pragma unroll
        for (int tt = 0; tt < 16; ++tt) acc[rc][tt] = 0.f;
    for (int e = 0; e < 256; ++e) {
        float xv[16];
        #pragma unroll
        for (int tt = 0; tt < 16; ++tt) xv[tt] = xt[tt][e];
        #pragma unroll
        for (int rc = 0; rc < 4; ++rc) {
            float w = W[(size_t)(rc * 256 + tid) * 256 + e];
            #pragma unroll
            for (int tt = 0; tt < 16; ++tt) acc[rc][tt] += w * xv[tt];
        }
    }
    const float* bih = dir ? bihb : bihf;
    const float* bhh = dir ? bhhb : bhhf;
    float b0 = bih[0 * 256 + tid] + bhh[0 * 256 + tid];
    float b1 = bih[1 * 256 + tid] + bhh[1 * 256 + tid];
    float b2 = bih[2 * 256 + tid] + bhh[2 * 256 + tid];
    float b3 = bih[3 * 256 + tid] + bhh[3 * 256 + tid];
    #pragma unroll
    for (int tt = 0; tt < 16; ++tt) {
        float4 v;
        v.x = acc[0][tt] + b0;
        v.y = acc[1][tt] + b1;
        v.z = acc[2][tt] + b2;
        v.w = acc[3][tt] + b3;
        ((float4*)(xg + ((size_t)dir * S + (t0 + tt)) * 1024))[tid] = v;
    }
}

// ---------- K2: sequential LSTM, 256 threads, WHOLE CELL per thread ----------
// Thread m owns rows {m, 256+m, 512+m, 768+m} = i,f,g,o of cell m.
// No cross-lane gate exchange. Weights: Wi v32-63, Wf v64-95, Wg v96-127,
// Wo v128-159 (int4, 32 dwords each row). h v160-191. accs v192-195.
// xg cur v196-199, next v200-203. addrs v204-207. temps v208-219. c v220.
// scales v221-224. nibble shift v225.
#define D8(a,w,h) "v_dot8_i32_i4 " a ", " w ", " h ", " a "\n\t"
#define CH(H0,H1,H2,H3, I0,I1,I2,I3, F0,F1,F2,F3, G0,G1,G2,G3, O0,O1,O2,O3) \
 D8("v192",I0,H0) D8("v193",F0,H0) D8("v194",G0,H0) D8("v195",O0,H0) \
 D8("v192",I1,H1) D8("v193",F1,H1) D8("v194",G1,H1) D8("v195",O1,H1) \
 D8("v192",I2,H2) D8("v193",F2,H2) D8("v194",G2,H2) D8("v195",O2,H2) \
 D8("v192",I3,H3) D8("v193",F3,H3) D8("v194",G3,H3) D8("v195",O3,H3)

#define LSTM_BODY(XI, XF, XG, XO, NQUAD) \
  "global_load_dwordx4 " NQUAD ", v204, %[sxg]\n\t" \
  "ds_read_b128 v[160:163], v206\n\t" \
  "ds_read_b128 v[164:167], v206 offset:16\n\t" \
  "ds_read_b128 v[168:171], v206 offset:32\n\t" \
  "ds_read_b128 v[172:175], v206 offset:48\n\t" \
  "ds_read_b128 v[176:179], v206 offset:64\n\t" \
  "ds_read_b128 v[180:183], v206 offset:80\n\t" \
  "ds_read_b128 v[184:187], v206 offset:96\n\t" \
  "ds_read_b128 v[188:191], v206 offset:112\n\t" \
  "v_mov_b32 v192, 0\n\t" \
  "v_mov_b32 v193, 0\n\t" \
  "v_mov_b32 v194, 0\n\t" \
  "v_mov_b32 v195, 0\n\t" \
  "s_waitcnt lgkmcnt(7)\n\t" \
  CH("v160","v161","v162","v163", "v32","v33","v34","v35", "v64","v65","v66","v67", "v96","v97","v98","v99", "v128","v129","v130","v131") \
  "s_waitcnt lgkmcnt(6)\n\t" \
  CH("v164","v165","v166","v167", "v36","v37","v38","v39", "v68","v69","v70","v71", "v100","v101","v102","v103", "v132","v133","v134","v135") \
  "s_waitcnt lgkmcnt(5)\n\t" \
  CH("v168","v169","v170","v171", "v40","v41","v42","v43", "v72","v73","v74","v75", "v104","v105","v106","v107", "v136","v137","v138","v139") \
  "s_waitcnt lgkmcnt(4)\n\t" \
  CH("v172","v173","v174","v175", "v44","v45","v46","v47", "v76","v77","v78","v79", "v108","v109","v110","v111", "v140","v141","v142","v143") \
  "s_waitcnt lgkmcnt(3)\n\t" \
  CH("v176","v177","v178","v179", "v48","v49","v50","v51", "v80","v81","v82","v83", "v112","v113","v114","v115", "v144","v145","v146","v147") \
  "s_waitcnt lgkmcnt(2)\n\t" \
  CH("v180","v181","v182","v183", "v52","v53","v54","v55", "v84","v85","v86","v87", "v116","v117","v118","v119", "v148","v149","v150","v151") \
  "s_waitcnt lgkmcnt(1)\n\t" \
  CH("v184","v185","v186","v187", "v56","v57","v58","v59", "v88","v89","v90","v91", "v120","v121","v122","v123", "v152","v153","v154","v155") \
  "s_waitcnt lgkmcnt(0)\n\t" \
  CH("v188","v189","v190","v191", "v60","v61","v62","v63", "v92","v93","v94","v95", "v124","v125","v126","v127", "v156","v157","v158","v159") \
  "v_cvt_f32_i32 v208, v192\n\t" \
  "v_cvt_f32_i32 v209, v193\n\t" \
  "v_cvt_f32_i32 v210, v194\n\t" \
  "v_cvt_f32_i32 v211, v195\n\t" \
  "s_waitcnt vmcnt(2)\n\t" \
  "v_fma_f32 v212, %[sci], v208, " XI "\n\t" \
  "v_fma_f32 v213, %[scf], v209, " XF "\n\t" \
  "v_fma_f32 v214, %[scg], v210, " XG "\n\t" \
  "v_fma_f32 v215, %[sco], v211, " XO "\n\t" \
  "v_mul_f32 v208, %[nk], v212\n\t" \
  "v_mul_f32 v209, %[nk], v213\n\t" \
  "v_mul_f32 v211, %[nk], v215\n\t" \
  "v_med3_f32 v214, v214, %[ncl], %[pcl]\n\t" \
  "v_mul_f32 v210, %[k2], v214\n\t" \
  "v_exp_f32 v208, v208\n\t" \
  "v_exp_f32 v209, v209\n\t" \
  "v_exp_f32 v211, v211\n\t" \
  "v_exp_f32 v210, v210\n\t" \
  "s_nop 1\n\t" \
  "v_add_f32 v212, 1.0, v208\n\t" \
  "v_add_f32 v213, 1.0, v209\n\t" \
  "v_add_f32 v215, 1.0, v211\n\t" \
  "v_add_f32 v216, 1.0, v210\n\t" \
  "v_add_f32 v217, -1.0, v210\n\t" \
  "v_rcp_f32 v212, v212\n\t" \
  "v_rcp_f32 v213, v213\n\t" \
  "v_rcp_f32 v215, v215\n\t" \
  "v_rcp_f32 v216, v216\n\t" \
  "s_nop 1\n\t" \
  "v_mul_f32 v217, v217, v216\n\t" \
  "v_mul_f32 v220, v213, v220\n\t" \
  "v_fmac_f32 v220, v212, v217\n\t" \
  "v_med3_f32 v208, v220, %[ncl], %[pcl]\n\t" \
  "v_mul_f32 v208, %[k2], v208\n\t" \
  "v_exp_f32 v208, v208\n\t" \
  "s_nop 1\n\t" \
  "v_add_f32 v209, -1.0, v208\n\t" \
  "v_add_f32 v210, 1.0, v208\n\t" \
  "v_rcp_f32 v210, v210\n\t" \
  "s_nop 1\n\t" \
  "v_mul_f32 v209, v209, v210\n\t" \
  "v_mul_f32 v218, v215, v209\n\t" \
  "global_store_dword v205, v218, %[shs]\n\t" \
  "v_mul_f32 v208, %[c7], v218\n\t" \
  "v_rndne_f32 v208, v208\n\t" \
  "v_cvt_i32_f32 v208, v208\n\t" \
  "v_and_b32 v208, 15, v208\n\t" \
  "v_lshlrev_b32 v208, v225, v208\n\t" \
  "s_nop 1\n\t" \
  "v_mov_b32_dpp v209, v208 quad_perm:[1,0,3,2] row_mask:0xf bank_mask:0xf\n\t" \
  "v_or_b32 v208, v208, v209\n\t" \
  "s_nop 1\n\t" \
  "v_mov_b32_dpp v209, v208 quad_perm:[2,3,0,1] row_mask:0xf bank_mask:0xf\n\t" \
  "v_or_b32 v208, v208, v209\n\t" \
  "ds_write_b16 v207, v208\n\t" \
  "v_add_u32 v204, 0x1000, v204\n\t" \
  "v_add_u32 v205, 0x400, v205\n\t" \
  "v_xor_b32 v206, 0x80, v206\n\t" \
  "v_xor_b32 v207, 0x80, v207\n\t" \
  "s_waitcnt lgkmcnt(0)\n\t" \
  "s_barrier\n\t"

__global__ __launch_bounds__(256, 1) void lstm_kernel(
    const float* __restrict__ xg, const int* __restrict__ wq4,
    const float* __restrict__ wscale, const int* __restrict__ hq0p,
    const float* __restrict__ c0, float* __restrict__ hs)
{
    const int d = blockIdx.x;
    const int t = threadIdx.x;   // cell index 0..255

    __shared__ alignas(16) int hq4buf[256];  // 1KB: buf0 @0, buf1 @128, dump @512

    const int*   wq_d = wq4 + (size_t)d * 32768;
    const float* xg_d = xg + (size_t)d * S * 1024;
    float*       hs_d = hs + (size_t)d * S * 256;
    const float sci = wscale[d * 1024 + t]       * (1.0f / 7.0f);
    const float scf = wscale[d * 1024 + 256 + t] * (1.0f / 7.0f);
    const float scg = wscale[d * 1024 + 512 + t] * (1.0f / 7.0f);
    const float sco = wscale[d * 1024 + 768 + t] * (1.0f / 7.0f);
    const float c0v = c0[d * 256 + t];
    const int h0v = hq0p[d * 32 + (t & 31)];
    const unsigned h0a = (t < 32) ? (unsigned)t * 4u : (512u + (unsigned)(t & 63) * 4u);
    const unsigned xai = (unsigned)t * 16u;
    const unsigned hsi = (unsigned)t * 4u;
    const unsigned wad = ((t & 3) == 0) ? (128u + (unsigned)(t >> 1))
                                        : (512u + (unsigned)t * 2u);
    const unsigned voW = (unsigned)t * 128u;   // row m base; +0x8000 per gate
    const unsigned shf = (unsigned)(t & 3) * 4u;
    const float nk = -1.4426950408889634f;
    const float k2 = 2.8853900817779268f;
    const float c7 = 7.0f;
    const float ncl = -30.0f, pcl = 30.0f;
    const unsigned lds_keep = (unsigned)(size_t)&hq4buf[0];
    int cnt = S / 2;   // body unrolled x2

    asm volatile(
        // ---- prologue ----
        "v_mov_b32 v204, %[xai]\n\t"
        "v_mov_b32 v205, %[hsi]\n\t"
        "v_mov_b32 v206, 0\n\t"
        "v_mov_b32 v207, %[wad]\n\t"
        "v_mov_b32 v220, %[c0v]\n\t"
        "v_mov_b32 v221, %[sci]\n\t"
        "v_mov_b32 v222, %[scf]\n\t"
        "v_mov_b32 v223, %[scg]\n\t"
        "v_mov_b32 v224, %[sco]\n\t"
        "v_mov_b32 v225, %[shf]\n\t"
        "ds_write_b32 %[h0a], %[h0v]\n\t"
        "v_mov_b32 v208, %[voW]\n\t"
        "global_load_dwordx4 v[32:35], v208, %[swq]\n\t"
        "global_load_dwordx4 v[36:39], v208, %[swq] offset:16\n\t"
        "global_load_dwordx4 v[40:43], v208, %[swq] offset:32\n\t"
        "global_load_dwordx4 v[44:47], v208, %[swq] offset:48\n\t"
        "global_load_dwordx4 v[48:51], v208, %[swq] offset:64\n\t"
        "global_load_dwordx4 v[52:55], v208, %[swq] offset:80\n\t"
        "global_load_dwordx4 v[56:59], v208, %[swq] offset:96\n\t"
        "global_load_dwordx4 v[60:63], v208, %[swq] offset:112\n\t"
        "v_add_u32 v208, 0x8000, v208\n\t"
        "global_load_dwordx4 v[64:67], v208, %[swq]\n\t"
        "global_load_dwordx4 v[68:71], v208, %[swq] offset:16\n\t"
        "global_load_dwordx4 v[72:75], v208, %[swq] offset:32\n\t"
        "global_load_dwordx4 v[76:79], v208, %[swq] offset:48\n\t"
        "global_load_dwordx4 v[80:83], v208, %[swq] offset:64\n\t"
        "global_load_dwordx4 v[84:87], v208, %[swq] offset:80\n\t"
        "global_load_dwordx4 v[88:91], v208, %[swq] offset:96\n\t"
        "global_load_dwordx4 v[92:95], v208, %[swq] offset:112\n\t"
        "v_add_u32 v208, 0x8000, v208\n\t"
        "global_load_dwordx4 v[96:99],   v208, %[swq]\n\t"
        "global_load_dwordx4 v[100:103], v208, %[swq] offset:16\n\t"
        "global_load_dwordx4 v[104:107], v208, %[swq] offset:32\n\t"
        "global_load_dwordx4 v[108:111], v208, %[swq] offset:48\n\t"
        "global_load_dwordx4 v[112:115], v208, %[swq] offset:64\n\t"
        "global_load_dwordx4 v[116:119], v208, %[swq] offset:80\n\t"
        "global_load_dwordx4 v[120:123], v208, %[swq] offset:96\n\t"
        "global_load_dwordx4 v[124:127], v208, %[swq] offset:112\n\t"
        "v_add_u32 v208, 0x8000, v208\n\t"
        "global_load_dwordx4 v[128:131], v208, %[swq]\n\t"
        "global_load_dwordx4 v[132:135], v208, %[swq] offset:16\n\t"
        "global_load_dwordx4 v[136:139], v208, %[swq] offset:32\n\t"
        "global_load_dwordx4 v[140:143], v208, %[swq] offset:48\n\t"
        "global_load_dwordx4 v[144:147], v208, %[swq] offset:64\n\t"
        "global_load_dwordx4 v[148:151], v208, %[swq] offset:80\n\t"
        "global_load_dwordx4 v[152:155], v208, %[swq] offset:96\n\t"
        "global_load_dwordx4 v[156:159], v208, %[swq] offset:112\n\t"
        "global_load_dwordx4 v[196:199], v204, %[sxg]\n\t"
        "v_add_u32 v204, 0x1000, v204\n\t"
        "s_waitcnt vmcnt(0) lgkmcnt(0)\n\t"
        "s_barrier\n\t"
        // ---- main loop: 2 steps per iteration ----
        "Llstm%=:\n\t"
        LSTM_BODY("v196", "v197", "v198", "v199", "v[200:203]")
        LSTM_BODY("v200", "v201", "v202", "v203", "v[196:199]")
        "s_add_i32 %[cnt], %[cnt], -1\n\t"
        "s_cmp_lg_u32 %[cnt], 0\n\t"
        "s_cbranch_scc1 Llstm%=\n\t"
        : [cnt] "+s"(cnt)
        : [sxg] "s"(xg_d), [shs] "s"(hs_d), [swq] "s"(wq_d),
          [xai] "v"(xai), [hsi] "v"(hsi), [wad] "v"(wad),
          [c0v] "v"(c0v), [h0a] "v"(h0a), [h0v] "v"(h0v),
          [sci] "v"(sci), [scf] "v"(scf), [scg] "v"(scg), [sco] "v"(sco),
          [nk] "v"(nk), [k2] "v"(k2), [c7] "v"(c7),
          [ncl] "v"(ncl), [pcl] "v"(pcl),
          [voW] "v"(voW), [shf] "v"(shf), [keep] "v"(lds_keep)
        : "memory", "scc",
          "v32","v33","v34","v35","v36","v37","v38","v39",
          "v40","v41","v42","v43","v44","v45","v46","v47",
          "v48","v49","v50","v51","v52","v53","v54","v55",
          "v56","v57","v58","v59","v60","v61","v62","v63",
          "v64","v65","v66","v67","v68","v69","v70","v71",
          "v72","v73","v74","v75","v76","v77","v78","v79",
          "v80","v81","v82","v83","v84","v85","v86","v87",
          "v88","v89","v90","v91","v92","v93","v94","v95",
          "v96","v97","v98","v99","v100","v101","v102","v103",
          "v104","v105","v106","v107","v108","v109","v110","v111",
          "v112","v113","v114","v115","v116","v117","v118","v119",
          "v120","v121","v122","v123","v124","v125","v126","v127",
          "v128","v129","v130","v131","v132","v133","v134","v135",
          "v136","v137","v138","v139","v140","v141","v142","v143",
          "v144","v145","v146","v147","v148","v149","v150","v151",
          "v152","v153","v154","v155","v156","v157","v158","v159",
          "v160","v161","v162","v163","v164","v165","v166","v167",
          "v168","v169","v170","v171","v172","v173","v174","v175",
          "v176","v177","v178","v179","v180","v181","v182","v183",
          "v184","v185","v186","v187","v188","v189","v190","v191",
          "v192","v193","v194","v195","v196","v197","v198","v199",
          "v200","v201","v202","v203","v204","v205","v206","v207",
          "v208","v209","v210","v211","v212","v213","v214","v215",
          "v216","v217","v218","v219","v220","v221","v222","v223",
          "v224","v225");
}

// ---------- K3: feats[t][tag] = b_out[tag] + W_out[tag] . [hf[t], hb[t]] ----------
__global__ __launch_bounds__(256) void feats_kernel(
    const float* __restrict__ hs, const float* __restrict__ Wout,
    const float* __restrict__ bout, float* __restrict__ feats)
{
    __shared__ float Wl[16][513];
    int tid = threadIdx.x;
    for (int i = tid; i < 16 * 512; i += 256) Wl[i >> 9][i & 511] = Wout[i];
    __syncthreads();
    int tt = tid >> 4, tag = tid & 15;
    int tcur = blockIdx.x * 16 + tt;
    const float* hf = hs + (size_t)tcur * 256;
    const float* hb = hs + (size_t)S * 256 + (size_t)(S - 1 - tcur) * 256;
    float acc = bout[tag];
    for (int k = 0; k < 256; ++k) acc += Wl[tag][k] * hf[k];
    for (int k = 0; k < 256; ++k) acc += Wl[tag][256 + k] * hb[k];
    feats[(size_t)tcur * 16 + tag] = acc;
}

// ---------- K4a: CRF chunk products in log semiring ----------
__global__ __launch_bounds__(256) void crf_chunk_kernel(
    const float* __restrict__ feats, const float* __restrict__ trans,
    float* __restrict__ P)
{
    int chunk = blockIdx.x;
    int tid = threadIdx.x;
    int i = tid >> 4, jj = tid & 15;
    __shared__ float Mt[2][16][17];   // Mt[buf][j][k] = M[k][j]
    float tr[16];
    #pragma unroll
    for (int k = 0; k < 16; ++k) tr[k] = trans[i * 16 + k];
    int t0 = chunk * 64;
    float emit = feats[(size_t)t0 * 16 + i];
    Mt[0][jj][i] = tr[jj] + emit;     // init M = A_{t0}
    __syncthreads();
    int cur = 0;
    float em_next = feats[(size_t)(t0 + 1) * 16 + i];
    for (int s = 1; s < 64; ++s) {
        float em = em_next;
        if (s + 1 < 64) em_next = feats[(size_t)(t0 + s + 1) * 16 + i];
        float v[16];
        #pragma unroll
        for (int k = 0; k < 16; ++k) v[k] = tr[k] + Mt[cur][jj][k];
        float m = v[0];
        #pragma unroll
        for (int k = 1; k < 16; ++k) m = fmaxf(m, v[k]);
        float ssum = 0.f;
        #pragma unroll
        for (int k = 0; k < 16; ++k) ssum += fast_exp(v[k] - m);
        float nv = em + m + fast_log(ssum);
        Mt[cur ^ 1][jj][i] = nv;
        cur ^= 1;
        __syncthreads();
    }
    P[((size_t)chunk * 16 + i) * 16 + jj] = Mt[cur][jj][i];
}

// ---------- K4b: fold 64 chunk matrices through alpha ----------
__global__ __launch_bounds__(256) void crf_fold_kernel(
    const float* __restrict__ P, const float* __restrict__ trans,
    float* __restrict__ out)
{
    int tid = threadIdx.x;
    int i = tid >> 4, jj = tid & 15;
    __shared__ float alpha[16];
    if (tid < 16) alpha[tid] = (tid == START_) ? 0.0f : NEG_;
    __syncthreads();
    for (int cc = 0; cc < 64; ++cc) {
        float pv = P[((size_t)cc * 16 + i) * 16 + jj];
        float v = pv + alpha[jj];
        float m = v;
        #pragma unroll
        for (int off = 1; off < 16; off <<= 1) m = fmaxf(m, __shfl_xor(m, off, 64));
        float e = fast_exp(v - m);
        #pragma unroll
        for (int off = 1; off < 16; off <<= 1) e += __shfl_xor(e, off, 64);
        float nv = m + fast_log(e);
        __syncthreads();
        if (jj == 0) alpha[i] = nv;
        __syncthreads();
    }
    if (tid < 16) {
        float v = alpha[tid] + trans[STOP_ * 16 + tid];
        float m = v;
        #pragma unroll
        for (int off = 1; off < 16; off <<= 1) m = fmaxf(m, __shfl_xor(m, off, 64));
        float e = fast_exp(v - m);
        #pragma unroll
        for (int off = 1; off < 16; off <<= 1) e += __shfl_xor(e, off, 64);
        if (tid == 0) out[0] = m + fast_log(e);
    }
}

extern "C" void kernel_launch(void* const* d_in, const int* in_sizes, int n_in,
                              void* d_out, int out_size, void* d_ws, size_t ws_size,
                              hipStream_t stream) {
    const int*   sent  = (const int*)d_in[0];
    const float* embed = (const float*)d_in[1];
    const float* Wihf  = (const float*)d_in[2];
    const float* Whhf  = (const float*)d_in[3];
    const float* bihf  = (const float*)d_in[4];
    const float* bhhf  = (const float*)d_in[5];
    const float* Wihb  = (const float*)d_in[6];
    const float* Whhb  = (const float*)d_in[7];
    const float* bihb  = (const float*)d_in[8];
    const float* bhhb  = (const float*)d_in[9];
    const float* Wout  = (const float*)d_in[10];
    const float* bout  = (const float*)d_in[11];
    const float* trans = (const float*)d_in[12];
    const float* h0    = (const float*)d_in[13];
    const float* c0    = (const float*)d_in[14];
    float* out = (float*)d_out;

    char* ws = (char*)d_ws;
    constexpr size_t OFF_XG     = 0;                                      // 32MB
    constexpr size_t OFF_WQ     = OFF_XG + (size_t)2 * S * 1024 * 4;      // 256KB (int4)
    constexpr size_t OFF_WSCALE = OFF_WQ + (size_t)2 * 1024 * 32 * 4;     // 8KB
    constexpr size_t OFF_HQ0    = OFF_WSCALE + 2 * 1024 * 4;              // 256B
    constexpr size_t OFF_SH0    = OFF_HQ0 + 2 * 32 * 4;                   // pad 256B
    constexpr size_t OFF_HS     = OFF_SH0 + 256;                          // 8MB
    constexpr size_t OFF_FEATS  = OFF_HS + (size_t)2 * S * 256 * 4;       // 256KB
    constexpr size_t OFF_P      = OFF_FEATS + (size_t)S * 16 * 4;         // 64KB

    float* xg     = (float*)(ws + OFF_XG);
    int*   wq4    = (int*)(ws + OFF_WQ);
    float* wscale = (float*)(ws + OFF_WSCALE);
    int*   hq0p   = (int*)(ws + OFF_HQ0);
    float* sh0    = (float*)(ws + OFF_SH0);
    float* hs     = (float*)(ws + OFF_HS);
    float* feats  = (float*)(ws + OFF_FEATS);
    float* P      = (float*)(ws + OFF_P);

    quant4_kernel<<<dim3(2050), dim3(64), 0, stream>>>(Whhf, Whhb, h0, wq4, wscale, hq0p, sh0);
    xg_kernel<<<dim3(256, 2), dim3(256), 0, stream>>>(sent, embed, Wihf, bihf, bhhf,
                                                      Wihb, bihb, bhhb, xg);
    lstm_kernel<<<dim3(2), dim3(256), 0, stream>>>(xg, wq4, wscale, hq0p, c0, hs);
    feats_kernel<<<dim3(256), dim3(256), 0, stream>>>(hs, Wout, bout, feats);
    crf_chunk_kernel<<<dim3(64), dim3(256), 0, stream>>>(feats, trans, P);
    crf_fold_kernel<<<dim3(1), dim3(256), 0, stream>>>(P, trans, out);
}

// Round 10
// 2153.043 us; speedup vs baseline: 1.3714x; 1.0970x over previous
//
#include <hip/hip_runtime.h>
#include <hip/hip_bf16.h>

#define S 4096
#define E 256
#define HH 256
#define TT 16
#define NEG_ -10000.0f
#define START_ 14
#define STOP_ 15
// hs layout: per direction [256-float slack row][S*256 data]
#define DSTRIDE_F (S * 256 + 256)

// ---------- fast math helpers (host-side kernels) ----------
__device__ __forceinline__ float fast_exp(float x) {           // e^x
    return __builtin_amdgcn_exp2f(x * 1.4426950408889634f);
}
__device__ __forceinline__ float fast_log(float x) {           // ln
    return 0.6931471805599453f * __builtin_amdgcn_logf(x);
}

// ---------- K0: quantize W_hh to int4 (per-row scale m/7); h0 FIXED 1/7 ----------
__global__ __launch_bounds__(64) void quant4_kernel(
    const float* __restrict__ Wf, const float* __restrict__ Wb,
    const float* __restrict__ h0,
    int* __restrict__ wq4, float* __restrict__ wscale,
    int* __restrict__ hq0p)
{
    int blk = blockIdx.x, lane = threadIdx.x;
    const float* src;
    int* dst;
    float* scl = nullptr;
    bool fixed = false;
    if (blk < 2048) {
        int d = blk >> 10, r = blk & 1023;
        src = (d == 0 ? Wf : Wb) + (size_t)r * 256;
        dst = wq4 + ((size_t)(d * 1024 + r)) * 32;
        scl = wscale + (d * 1024 + r);
    } else {
        int d = blk - 2048;
        src = h0 + (size_t)d * 256;
        dst = hq0p + d * 32;
        fixed = true;   // h0 quantized at steady-state scale 1/7 (clamped)
    }
    float4 a = make_float4(0.f, 0.f, 0.f, 0.f), b = a;
    if (lane < 32) {
        a = ((const float4*)src)[2 * lane];
        b = ((const float4*)src)[2 * lane + 1];
    }
    float f[8] = {a.x, a.y, a.z, a.w, b.x, b.y, b.z, b.w};
    float m = 0.f;
    #pragma unroll
    for (int k = 0; k < 8; ++k) m = fmaxf(m, fabsf(f[k]));
    #pragma unroll
    for (int off = 1; off < 64; off <<= 1) m = fmaxf(m, __shfl_xor(m, off, 64));
    m = fmaxf(m, 1e-20f);
    float inv = fixed ? 7.0f : (7.0f / m);
    if (lane < 32) {
        int dw = 0;
        #pragma unroll
        for (int k = 0; k < 8; ++k) {
            int q = __float2int_rn(f[k] * inv);
            q = max(-8, min(7, q));
            dw |= (q & 0xF) << (4 * k);
        }
        dst[lane] = dw;
    }
    if (!fixed && lane == 0) *scl = m / 7.0f;
}

// ---------- K0b: transpose W_ih -> WT[dir][e][r] for coalesced xg reads ----------
__global__ __launch_bounds__(256) void transpose_kernel(
    const float* __restrict__ Wf, const float* __restrict__ Wb,
    float* __restrict__ WT)
{
    __shared__ float tile[32][33];
    const int dir = blockIdx.z;
    const float* W = dir ? Wb : Wf;
    const int r0 = blockIdx.x * 32, e0 = blockIdx.y * 32;
    const int tr = threadIdx.x & 31, tc = threadIdx.x >> 5;   // 32 x 8
    #pragma unroll
    for (int i = 0; i < 32; i += 8)
        tile[tc + i][tr] = W[(size_t)(r0 + tc + i) * 256 + e0 + tr];
    __syncthreads();
    float* out = WT + (size_t)dir * 256 * 1024;
    #pragma unroll
    for (int i = 0; i < 32; i += 8)
        out[(size_t)(e0 + tc + i) * 1024 + r0 + tr] = tile[tr][tc + i];
}

// ---------- K1: xg (coalesced via WT), stored float4 {i,f,g,o} per cell ----------
__global__ __launch_bounds__(256) void xg_kernel(
    const int* __restrict__ sent, const float* __restrict__ embed,
    const float* __restrict__ WT,
    const float* __restrict__ bihf, const float* __restrict__ bhhf,
    const float* __restrict__ bihb, const float* __restrict__ bhhb,
    float* __restrict__ xg)
{
    const int dir = blockIdx.y;
    const int t0 = blockIdx.x * 16;
    const int tid = threadIdx.x;
    const float* Wt = WT + (size_t)dir * 256 * 1024;
    __shared__ float xt[16][256];
    for (int tt = 0; tt < 16; ++tt) {
        int t = t0 + tt;
        int pos = dir ? (S - 1 - t) : t;
        int w = sent[pos];
        xt[tt][tid] = embed[(size_t)w * 256 + tid];
    }
    __syncthreads();
    float acc[4][16];
    #pragma unroll
    for (int rc = 0; rc < 4; ++rc)
        #pragma unroll
        for (int tt = 0; tt < 16; ++tt) acc[rc][tt] = 0.f;
    for (int e = 0; e < 256; ++e) {
        float xv[16];
        #pragma unroll
        for (int tt = 0; tt < 16; ++tt) xv[tt] = xt[tt][e];
        const float* wrow = Wt + (size_t)e * 1024;
        #pragma unroll
        for (int rc = 0; rc < 4; ++rc) {
            float w = wrow[rc * 256 + tid];        // consecutive tid -> coalesced
            #pragma unroll
            for (int tt = 0; tt < 16; ++tt) acc[rc][tt] += w * xv[tt];
        }
    }
    const float* bih = dir ? bihb : bihf;
    const float* bhh = dir ? bhhb : bhhf;
    float b0 = bih[0 * 256 + tid] + bhh[0 * 256 + tid];
    float b1 = bih[1 * 256 + tid] + bhh[1 * 256 + tid];
    float b2 = bih[2 * 256 + tid] + bhh[2 * 256 + tid];
    float b3 = bih[3 * 256 + tid] + bhh[3 * 256 + tid];
    #pragma unroll
    for (int tt = 0; tt < 16; ++tt) {
        float4 v;
        v.x = acc[0][tt] + b0;
        v.y = acc[1][tt] + b1;
        v.z = acc[2][tt] + b2;
        v.w = acc[3][tt] + b3;
        ((float4*)(xg + ((size_t)dir * S + (t0 + tt)) * 1024))[tid] = v;
    }
}

// ---------- K2: sequential LSTM, 256 threads, whole cell per thread ----------
// DEPTH-1 xg pipeline (R9's depth-2 prologue without retargeted body loads
// shifted consumption by one step and read OOB NaN bit patterns -> reverted).
// Body k: consumes quad loaded in body k-1; issues store(h_{k-1}) + load(k+1).
// vmcnt(2) = this body's {store,load} outstanding, previous load retired.
#define D8(a,w,h) "v_dot8_i32_i4 " a ", " w ", " h ", " a "\n\t"
#define CH(H0,H1,H2,H3, I0,I1,I2,I3, F0,F1,F2,F3, G0,G1,G2,G3, O0,O1,O2,O3) \
 D8("v192",I0,H0) D8("v193",F0,H0) D8("v194",G0,H0) D8("v195",O0,H0) \
 D8("v192",I1,H1) D8("v193",F1,H1) D8("v194",G1,H1) D8("v195",O1,H1) \
 D8("v192",I2,H2) D8("v193",F2,H2) D8("v194",G2,H2) D8("v195",O2,H2) \
 D8("v192",I3,H3) D8("v193",F3,H3) D8("v194",G3,H3) D8("v195",O3,H3)

#define LSTM_BODY(XI, XF, XG, XO, NQUAD) \
  "ds_read_b128 v[160:163], v206\n\t" \
  "ds_read_b128 v[164:167], v206 offset:16\n\t" \
  "ds_read_b128 v[168:171], v206 offset:32\n\t" \
  "ds_read_b128 v[172:175], v206 offset:48\n\t" \
  "ds_read_b128 v[176:179], v206 offset:64\n\t" \
  "ds_read_b128 v[180:183], v206 offset:80\n\t" \
  "ds_read_b128 v[184:187], v206 offset:96\n\t" \
  "ds_read_b128 v[188:191], v206 offset:112\n\t" \
  "v_xor_b32 v206, 0x80, v206\n\t" \
  "global_store_dword v205, v218, %[shs]\n\t" \
  "v_add_u32 v205, 0x400, v205\n\t" \
  "global_load_dwordx4 " NQUAD ", v204, %[sxg]\n\t" \
  "v_add_u32 v204, 0x1000, v204\n\t" \
  "s_waitcnt lgkmcnt(7)\n\t" \
  CH("v160","v161","v162","v163", "v32","v33","v34","v35", "v64","v65","v66","v67", "v96","v97","v98","v99", "v128","v129","v130","v131") \
  "s_waitcnt lgkmcnt(6)\n\t" \
  CH("v164","v165","v166","v167", "v36","v37","v38","v39", "v68","v69","v70","v71", "v100","v101","v102","v103", "v132","v133","v134","v135") \
  "s_waitcnt lgkmcnt(5)\n\t" \
  CH("v168","v169","v170","v171", "v40","v41","v42","v43", "v72","v73","v74","v75", "v104","v105","v106","v107", "v136","v137","v138","v139") \
  "s_waitcnt lgkmcnt(4)\n\t" \
  CH("v172","v173","v174","v175", "v44","v45","v46","v47", "v76","v77","v78","v79", "v108","v109","v110","v111", "v140","v141","v142","v143") \
  "s_waitcnt lgkmcnt(3)\n\t" \
  CH("v176","v177","v178","v179", "v48","v49","v50","v51", "v80","v81","v82","v83", "v112","v113","v114","v115", "v144","v145","v146","v147") \
  "s_waitcnt lgkmcnt(2)\n\t" \
  CH("v180","v181","v182","v183", "v52","v53","v54","v55", "v84","v85","v86","v87", "v116","v117","v118","v119", "v148","v149","v150","v151") \
  "s_waitcnt lgkmcnt(1)\n\t" \
  CH("v184","v185","v186","v187", "v56","v57","v58","v59", "v88","v89","v90","v91", "v120","v121","v122","v123", "v152","v153","v154","v155") \
  "s_waitcnt lgkmcnt(0)\n\t" \
  CH("v188","v189","v190","v191", "v60","v61","v62","v63", "v92","v93","v94","v95", "v124","v125","v126","v127", "v156","v157","v158","v159") \
  "v_cvt_f32_i32 v208, v192\n\t" \
  "v_cvt_f32_i32 v209, v193\n\t" \
  "v_cvt_f32_i32 v210, v194\n\t" \
  "v_cvt_f32_i32 v211, v195\n\t" \
  "s_waitcnt vmcnt(2)\n\t" \
  "v_fma_f32 v212, %[sci], v208, " XI "\n\t" \
  "v_fma_f32 v213, %[scf], v209, " XF "\n\t" \
  "v_fma_f32 v214, %[scg], v210, " XG "\n\t" \
  "v_fma_f32 v215, %[sco], v211, " XO "\n\t" \
  "v_mul_f32 v208, %[nk], v212\n\t" \
  "v_mul_f32 v209, %[nk], v213\n\t" \
  "v_mul_f32 v211, %[nk], v215\n\t" \
  "v_med3_f32 v214, v214, %[ncl], %[pcl]\n\t" \
  "v_mul_f32 v210, %[k2], v214\n\t" \
  "v_exp_f32 v208, v208\n\t" \
  "v_exp_f32 v209, v209\n\t" \
  "v_exp_f32 v211, v211\n\t" \
  "v_exp_f32 v210, v210\n\t" \
  "s_nop 1\n\t" \
  "v_add_f32 v212, 1.0, v208\n\t" \
  "v_add_f32 v213, 1.0, v209\n\t" \
  "v_add_f32 v215, 1.0, v211\n\t" \
  "v_add_f32 v216, 1.0, v210\n\t" \
  "v_add_f32 v217, -1.0, v210\n\t" \
  "v_rcp_f32 v212, v212\n\t" \
  "v_rcp_f32 v213, v213\n\t" \
  "v_rcp_f32 v215, v215\n\t" \
  "v_rcp_f32 v216, v216\n\t" \
  "s_nop 1\n\t" \
  "v_mul_f32 v217, v217, v216\n\t" \
  "v_mul_f32 v219, %[c7], v215\n\t" \
  "v_mul_f32 v220, v213, v220\n\t" \
  "v_fmac_f32 v220, v212, v217\n\t" \
  "v_med3_f32 v208, v220, %[ncl], %[pcl]\n\t" \
  "v_mul_f32 v208, %[k2], v208\n\t" \
  "v_exp_f32 v208, v208\n\t" \
  "s_nop 1\n\t" \
  "v_add_f32 v209, -1.0, v208\n\t" \
  "v_add_f32 v210, 1.0, v208\n\t" \
  "v_rcp_f32 v210, v210\n\t" \
  "s_nop 1\n\t" \
  "v_mul_f32 v209, v209, v210\n\t" \
  "v_mul_f32 v217, v219, v209\n\t" \
  "v_add_f32 v208, 0x4b400000, v217\n\t" \
  "v_and_b32 v208, 15, v208\n\t" \
  "v_lshlrev_b32 v208, v225, v208\n\t" \
  "v_mul_f32 v218, %[i7], v217\n\t" \
  "s_nop 1\n\t" \
  "v_mov_b32_dpp v209, v208 quad_perm:[1,0,3,2] row_mask:0xf bank_mask:0xf\n\t" \
  "v_or_b32 v208, v208, v209\n\t" \
  "s_nop 1\n\t" \
  "v_mov_b32_dpp v209, v208 quad_perm:[2,3,0,1] row_mask:0xf bank_mask:0xf\n\t" \
  "v_or_b32 v208, v208, v209\n\t" \
  "ds_write_b16 v207, v208\n\t" \
  "v_xor_b32 v207, 0x80, v207\n\t" \
  "v_mov_b32 v192, 0\n\t" \
  "v_mov_b32 v193, 0\n\t" \
  "v_mov_b32 v194, 0\n\t" \
  "v_mov_b32 v195, 0\n\t" \
  "s_waitcnt lgkmcnt(0)\n\t" \
  "s_barrier\n\t"

__global__ __launch_bounds__(256, 1) void lstm_kernel(
    const float* __restrict__ xg, const int* __restrict__ wq4,
    const float* __restrict__ wscale, const int* __restrict__ hq0p,
    const float* __restrict__ c0, float* __restrict__ hs)
{
    const int d = blockIdx.x;
    const int t = threadIdx.x;   // cell index 0..255

    __shared__ alignas(16) int hq4buf[512];  // 2KB: buf0 @0, buf1 @128B, dump @512B

    const int*   wq_d = wq4 + (size_t)d * 32768;
    const float* xg_d = xg + (size_t)d * S * 1024;
    float*       hs_d = hs + (size_t)d * DSTRIDE_F;   // slack row first
    const float sci = wscale[d * 1024 + t]       * (1.0f / 7.0f);
    const float scf = wscale[d * 1024 + 256 + t] * (1.0f / 7.0f);
    const float scg = wscale[d * 1024 + 512 + t] * (1.0f / 7.0f);
    const float sco = wscale[d * 1024 + 768 + t] * (1.0f / 7.0f);
    const float c0v = c0[d * 256 + t];
    const int h0v = hq0p[d * 32 + (t & 31)];
    const unsigned h0a = (t < 32) ? (unsigned)t * 4u : (1536u + (unsigned)(t & 63) * 4u);
    const unsigned xai = (unsigned)t * 16u;
    const unsigned hsi = (unsigned)t * 4u;      // first (lagged) store -> slack row
    const unsigned wad = ((t & 3) == 0) ? (128u + (unsigned)(t >> 1))
                                        : (512u + (unsigned)((t & 255) << 2));
    const unsigned voW = (unsigned)t * 128u;   // row m base; +0x8000 per gate
    const unsigned shf = (unsigned)(t & 3) * 4u;
    const float nk = -1.4426950408889634f;
    const float k2 = 2.8853900817779268f;
    const float c7 = 7.0f;
    const float i7 = 1.0f / 7.0f;
    const float ncl = -30.0f, pcl = 30.0f;
    const unsigned lds_keep = (unsigned)(size_t)&hq4buf[0];
    int cnt = S / 2;   // body unrolled x2

    asm volatile(
        // ---- prologue ----
        "v_mov_b32 v204, %[xai]\n\t"
        "v_mov_b32 v205, %[hsi]\n\t"
        "v_mov_b32 v206, 0\n\t"
        "v_mov_b32 v207, %[wad]\n\t"
        "v_mov_b32 v218, 0\n\t"
        "v_mov_b32 v220, %[c0v]\n\t"
        "v_mov_b32 v225, %[shf]\n\t"
        "v_mov_b32 v192, 0\n\t"
        "v_mov_b32 v193, 0\n\t"
        "v_mov_b32 v194, 0\n\t"
        "v_mov_b32 v195, 0\n\t"
        "ds_write_b32 %[h0a], %[h0v]\n\t"
        "v_mov_b32 v208, %[voW]\n\t"
        "global_load_dwordx4 v[32:35], v208, %[swq]\n\t"
        "global_load_dwordx4 v[36:39], v208, %[swq] offset:16\n\t"
        "global_load_dwordx4 v[40:43], v208, %[swq] offset:32\n\t"
        "global_load_dwordx4 v[44:47], v208, %[swq] offset:48\n\t"
        "global_load_dwordx4 v[48:51], v208, %[swq] offset:64\n\t"
        "global_load_dwordx4 v[52:55], v208, %[swq] offset:80\n\t"
        "global_load_dwordx4 v[56:59], v208, %[swq] offset:96\n\t"
        "global_load_dwordx4 v[60:63], v208, %[swq] offset:112\n\t"
        "v_add_u32 v208, 0x8000, v208\n\t"
        "global_load_dwordx4 v[64:67], v208, %[swq]\n\t"
        "global_load_dwordx4 v[68:71], v208, %[swq] offset:16\n\t"
        "global_load_dwordx4 v[72:75], v208, %[swq] offset:32\n\t"
        "global_load_dwordx4 v[76:79], v208, %[swq] offset:48\n\t"
        "global_load_dwordx4 v[80:83], v208, %[swq] offset:64\n\t"
        "global_load_dwordx4 v[84:87], v208, %[swq] offset:80\n\t"
        "global_load_dwordx4 v[88:91], v208, %[swq] offset:96\n\t"
        "global_load_dwordx4 v[92:95], v208, %[swq] offset:112\n\t"
        "v_add_u32 v208, 0x8000, v208\n\t"
        "global_load_dwordx4 v[96:99],   v208, %[swq]\n\t"
        "global_load_dwordx4 v[100:103], v208, %[swq] offset:16\n\t"
        "global_load_dwordx4 v[104:107], v208, %[swq] offset:32\n\t"
        "global_load_dwordx4 v[108:111], v208, %[swq] offset:48\n\t"
        "global_load_dwordx4 v[112:115], v208, %[swq] offset:64\n\t"
        "global_load_dwordx4 v[116:119], v208, %[swq] offset:80\n\t"
        "global_load_dwordx4 v[120:123], v208, %[swq] offset:96\n\t"
        "global_load_dwordx4 v[124:127], v208, %[swq] offset:112\n\t"
        "v_add_u32 v208, 0x8000, v208\n\t"
        "global_load_dwordx4 v[128:131], v208, %[swq]\n\t"
        "global_load_dwordx4 v[132:135], v208, %[swq] offset:16\n\t"
        "global_load_dwordx4 v[136:139], v208, %[swq] offset:32\n\t"
        "global_load_dwordx4 v[140:143], v208, %[swq] offset:48\n\t"
        "global_load_dwordx4 v[144:147], v208, %[swq] offset:64\n\t"
        "global_load_dwordx4 v[148:151], v208, %[swq] offset:80\n\t"
        "global_load_dwordx4 v[152:155], v208, %[swq] offset:96\n\t"
        "global_load_dwordx4 v[156:159], v208, %[swq] offset:112\n\t"
        "global_load_dwordx4 v[196:199], v204, %[sxg]\n\t"
        "v_add_u32 v204, 0x1000, v204\n\t"
        "s_waitcnt vmcnt(0) lgkmcnt(0)\n\t"
        "s_barrier\n\t"
        // ---- main loop: 2 steps per iteration (depth-1 xg rotation) ----
        "Llstm%=:\n\t"
        LSTM_BODY("v196", "v197", "v198", "v199", "v[200:203]")
        LSTM_BODY("v200", "v201", "v202", "v203", "v[196:199]")
        "s_add_i32 %[cnt], %[cnt], -1\n\t"
        "s_cmp_lg_u32 %[cnt], 0\n\t"
        "s_cbranch_scc1 Llstm%=\n\t"
        // ---- epilogue: store last h ----
        "global_store_dword v205, v218, %[shs]\n\t"
        : [cnt] "+s"(cnt)
        : [sxg] "s"(xg_d), [shs] "s"(hs_d), [swq] "s"(wq_d),
          [xai] "v"(xai), [hsi] "v"(hsi), [wad] "v"(wad),
          [c0v] "v"(c0v), [h0a] "v"(h0a), [h0v] "v"(h0v),
          [sci] "v"(sci), [scf] "v"(scf), [scg] "v"(scg), [sco] "v"(sco),
          [nk] "v"(nk), [k2] "v"(k2), [c7] "v"(c7), [i7] "v"(i7),
          [ncl] "v"(ncl), [pcl] "v"(pcl),
          [voW] "v"(voW), [shf] "v"(shf), [keep] "v"(lds_keep)
        : "memory", "scc",
          "v32","v33","v34","v35","v36","v37","v38","v39",
          "v40","v41","v42","v43","v44","v45","v46","v47",
          "v48","v49","v50","v51","v52","v53","v54","v55",
          "v56","v57","v58","v59","v60","v61","v62","v63",
          "v64","v65","v66","v67","v68","v69","v70","v71",
          "v72","v73","v74","v75","v76","v77","v78","v79",
          "v80","v81","v82","v83","v84","v85","v86","v87",
          "v88","v89","v90","v91","v92","v93","v94","v95",
          "v96","v97","v98","v99","v100","v101","v102","v103",
          "v104","v105","v106","v107","v108","v109","v110","v111",
          "v112","v113","v114","v115","v116","v117","v118","v119",
          "v120","v121","v122","v123","v124","v125","v126","v127",
          "v128","v129","v130","v131","v132","v133","v134","v135",
          "v136","v137","v138","v139","v140","v141","v142","v143",
          "v144","v145","v146","v147","v148","v149","v150","v151",
          "v152","v153","v154","v155","v156","v157","v158","v159",
          "v160","v161","v162","v163","v164","v165","v166","v167",
          "v168","v169","v170","v171","v172","v173","v174","v175",
          "v176","v177","v178","v179","v180","v181","v182","v183",
          "v184","v185","v186","v187","v188","v189","v190","v191",
          "v192","v193","v194","v195","v196","v197","v198","v199",
          "v200","v201","v202","v203","v204","v205","v206","v207",
          "v208","v209","v210","v211","v212","v213","v214","v215",
          "v216","v217","v218","v219","v220","v221","v222","v223",
          "v224","v225");
}

// ---------- K3: feats[t][tag] = b_out[tag] + W_out[tag] . [hf[t], hb[t]] ----------
__global__ __launch_bounds__(256) void feats_kernel(
    const float* __restrict__ hsf, const float* __restrict__ hsb,
    const float* __restrict__ Wout,
    const float* __restrict__ bout, float* __restrict__ feats)
{
    __shared__ float Wl[16][513];
    int tid = threadIdx.x;
    for (int i = tid; i < 16 * 512; i += 256) Wl[i >> 9][i & 511] = Wout[i];
    __syncthreads();
    int tt = tid >> 4, tag = tid & 15;
    int tcur = blockIdx.x * 16 + tt;
    const float* hf = hsf + (size_t)tcur * 256;
    const float* hb = hsb + (size_t)(S - 1 - tcur) * 256;
    float acc = bout[tag];
    for (int k = 0; k < 256; ++k) acc += Wl[tag][k] * hf[k];
    for (int k = 0; k < 256; ++k) acc += Wl[tag][256 + k] * hb[k];
    feats[(size_t)tcur * 16 + tag] = acc;
}

// ---------- K4a: CRF chunk products in log semiring ----------
__global__ __launch_bounds__(256) void crf_chunk_kernel(
    const float* __restrict__ feats, const float* __restrict__ trans,
    float* __restrict__ P)
{
    int chunk = blockIdx.x;
    int tid = threadIdx.x;
    int i = tid >> 4, jj = tid & 15;
    __shared__ float Mt[2][16][17];   // Mt[buf][j][k] = M[k][j]
    float tr[16];
    #pragma unroll
    for (int k = 0; k < 16; ++k) tr[k] = trans[i * 16 + k];
    int t0 = chunk * 64;
    float emit = feats[(size_t)t0 * 16 + i];
    Mt[0][jj][i] = tr[jj] + emit;     // init M = A_{t0}
    __syncthreads();
    int cur = 0;
    float em_next = feats[(size_t)(t0 + 1) * 16 + i];
    for (int s = 1; s < 64; ++s) {
        float em = em_next;
        if (s + 1 < 64) em_next = feats[(size_t)(t0 + s + 1) * 16 + i];
        float v[16];
        #pragma unroll
        for (int k = 0; k < 16; ++k) v[k] = tr[k] + Mt[cur][jj][k];
        float m = v[0];
        #pragma unroll
        for (int k = 1; k < 16; ++k) m = fmaxf(m, v[k]);
        float ssum = 0.f;
        #pragma unroll
        for (int k = 0; k < 16; ++k) ssum += fast_exp(v[k] - m);
        float nv = em + m + fast_log(ssum);
        Mt[cur ^ 1][jj][i] = nv;
        cur ^= 1;
        __syncthreads();
    }
    P[((size_t)chunk * 16 + i) * 16 + jj] = Mt[cur][jj][i];
}

// ---------- K4b: fold 64 chunk matrices through alpha ----------
__global__ __launch_bounds__(256) void crf_fold_kernel(
    const float* __restrict__ P, const float* __restrict__ trans,
    float* __restrict__ out)
{
    int tid = threadIdx.x;
    int i = tid >> 4, jj = tid & 15;
    __shared__ float alpha[16];
    if (tid < 16) alpha[tid] = (tid == START_) ? 0.0f : NEG_;
    __syncthreads();
    for (int cc = 0; cc < 64; ++cc) {
        float pv = P[((size_t)cc * 16 + i) * 16 + jj];
        float v = pv + alpha[jj];
        float m = v;
        #pragma unroll
        for (int off = 1; off < 16; off <<= 1) m = fmaxf(m, __shfl_xor(m, off, 64));
        float e = fast_exp(v - m);
        #pragma unroll
        for (int off = 1; off < 16; off <<= 1) e += __shfl_xor(e, off, 64);
        float nv = m + fast_log(e);
        __syncthreads();
        if (jj == 0) alpha[i] = nv;
        __syncthreads();
    }
    if (tid < 16) {
        float v = alpha[tid] + trans[STOP_ * 16 + tid];
        float m = v;
        #pragma unroll
        for (int off = 1; off < 16; off <<= 1) m = fmaxf(m, __shfl_xor(m, off, 64));
        float e = fast_exp(v - m);
        #pragma unroll
        for (int off = 1; off < 16; off <<= 1) e += __shfl_xor(e, off, 64);
        if (tid == 0) out[0] = m + fast_log(e);
    }
}

extern "C" void kernel_launch(void* const* d_in, const int* in_sizes, int n_in,
                              void* d_out, int out_size, void* d_ws, size_t ws_size,
                              hipStream_t stream) {
    const int*   sent  = (const int*)d_in[0];
    const float* embed = (const float*)d_in[1];
    const float* Wihf  = (const float*)d_in[2];
    const float* Whhf  = (const float*)d_in[3];
    const float* bihf  = (const float*)d_in[4];
    const float* bhhf  = (const float*)d_in[5];
    const float* Wihb  = (const float*)d_in[6];
    const float* Whhb  = (const float*)d_in[7];
    const float* bihb  = (const float*)d_in[8];
    const float* bhhb  = (const float*)d_in[9];
    const float* Wout  = (const float*)d_in[10];
    const float* bout  = (const float*)d_in[11];
    const float* trans = (const float*)d_in[12];
    const float* h0    = (const float*)d_in[13];
    const float* c0    = (const float*)d_in[14];
    float* out = (float*)d_out;

    char* ws = (char*)d_ws;
    constexpr size_t OFF_XG     = 0;                                      // 32MB
    constexpr size_t OFF_WQ     = OFF_XG + (size_t)2 * S * 1024 * 4;      // 256KB (int4)
    constexpr size_t OFF_WSCALE = OFF_WQ + (size_t)2 * 1024 * 32 * 4;     // 8KB
    constexpr size_t OFF_HQ0    = OFF_WSCALE + 2 * 1024 * 4;              // 256B
    constexpr size_t OFF_WT     = OFF_HQ0 + 256;                          // 2MB
    constexpr size_t OFF_HS     = OFF_WT + (size_t)2 * 256 * 1024 * 4;    // 2*(4MB+1KB)
    constexpr size_t OFF_FEATS  = OFF_HS + (size_t)2 * DSTRIDE_F * 4;     // 256KB
    constexpr size_t OFF_P      = OFF_FEATS + (size_t)S * 16 * 4;         // 64KB

    float* xg     = (float*)(ws + OFF_XG);
    int*   wq4    = (int*)(ws + OFF_WQ);
    float* wscale = (float*)(ws + OFF_WSCALE);
    int*   hq0p   = (int*)(ws + OFF_HQ0);
    float* WT     = (float*)(ws + OFF_WT);
    float* hs     = (float*)(ws + OFF_HS);
    float* feats  = (float*)(ws + OFF_FEATS);
    float* P      = (float*)(ws + OFF_P);

    quant4_kernel<<<dim3(2050), dim3(64), 0, stream>>>(Whhf, Whhb, h0, wq4, wscale, hq0p);
    transpose_kernel<<<dim3(32, 8, 2), dim3(256), 0, stream>>>(Wihf, Wihb, WT);
    xg_kernel<<<dim3(256, 2), dim3(256), 0, stream>>>(sent, embed, WT, bihf, bhhf,
                                                      bihb, bhhb, xg);
    lstm_kernel<<<dim3(2), dim3(256), 0, stream>>>(xg, wq4, wscale, hq0p, c0, hs);
    feats_kernel<<<dim3(256), dim3(256), 0, stream>>>(hs + 256, hs + DSTRIDE_F + 256,
                                                      Wout, bout, feats);
    crf_chunk_kernel<<<dim3(64), dim3(256), 0, stream>>>(feats, trans, P);
    crf_fold_kernel<<<dim3(1), dim3(256), 0, stream>>>(P, trans, out);
}